// Round 10
// baseline (458.404 us; speedup 1.0000x reference)
//
#include <hip/hip_runtime.h>
#include <hip/hip_cooperative_groups.h>
#include <math.h>

namespace cg = cooperative_groups;

#define N_BOX 8192
#define NW 128              // 8192 / 64 words
#define LCAP 24576          // edges staged in LDS (96 KiB)
#define ECAP_MAX (1 << 21)  // max edges in global buffer (8 MiB)
#define THR_C 0.7f
#define IOU_THR_C 0.5f
#define EPS_C 1e-9f

// SCALER = max(3508/1280, 2480/1280) computed in double then rounded to f32,
// matching numpy/jax float32 weak-typed scalar promotion.
__device__ __constant__ float kScaler = (float)(3508.0 / 1280.0);

static __device__ __forceinline__ unsigned long long make_key(const float* conf, int i) {
    float c0 = conf[2 * i], c1 = conf[2 * i + 1];
    bool valid = (c0 > THR_C) || (c1 > THR_C);
    float ms = valid ? fmaxf(c0, c1) : -INFINITY;
    unsigned int u = __float_as_uint(ms);
    unsigned int m = (u & 0x80000000u) ? ~u : (u | 0x80000000u); // ascending map
    unsigned int d = ~m;                                          // descending key
    return ((unsigned long long)d << 32) | (unsigned int)i;
}

// LDS overlay: phases are separated by barriers, so one union serves all.
union SMem {
    unsigned long long sortbuf[N_BOX];            // 64 KiB (S1 uses first 2048)
    struct { float4 cb[64]; float carea[64]; } p; // pair tile
    struct {
        unsigned int eL[LCAP];                    // 96 KiB
        unsigned long long kL[NW], tL[NW], vL[NW];
        int chg[3];
    } j;                                          // ~99 KiB
};

// ---------------------------------------------------------------------------
// One cooperative kernel, 256 blocks x 1024 threads (1 block/CU), replacing
// 5 dispatches with 4 grid syncs. Phases (all individually verified in
// earlier rounds, code unchanged except thread-count strides):
//   S1: blocks 0-3 bitonic-sort 2048-chunks (global-index directions).
//   S2: blocks 0-1 fused k=4096 + k=8192 merge + gather (sb/order/validw/nv).
//   P : all blocks build the compact edge list over the nv x nv triangle.
//   J : block 0 Jacobi-iterates to the greedy-NMS fixpoint (unique, certified
//       by k_new==k_old); overflow falls back to on-the-fly serial greedy.
//   O : blocks 0-7 write the (N,6) output.
// ---------------------------------------------------------------------------
__global__ __launch_bounds__(1024) void mega_kernel(
        const float* __restrict__ conf,
        const float* __restrict__ bboxes,
        unsigned long long* __restrict__ keys,
        float4* __restrict__ sb,
        unsigned int* __restrict__ order,
        unsigned long long* __restrict__ validw,
        int* __restrict__ ecntE,
        int* __restrict__ nvD,
        unsigned int* __restrict__ edges,
        unsigned long long* __restrict__ keepK,
        float* __restrict__ out,
        int ecap) {
    __shared__ SMem sm;
    cg::grid_group grid = cg::this_grid();
    int bid = blockIdx.x;
    int t = threadIdx.x;
    int lane = t & 63;

    // ---------------- Phase S1: 4 blocks sort 2048-chunks ----------------
    if (bid < 4) {
        int base = bid * 2048;
        for (int l = t; l < 2048; l += 1024) sm.sortbuf[l] = make_key(conf, base + l);
        __syncthreads();
        for (int k = 2; k <= 2048; k <<= 1) {
            for (int j = k >> 1; j > 0; j >>= 1) {
                int i = ((t & ~(j - 1)) << 1) | (t & (j - 1));
                int p = i | j;
                bool up = (((base + i) & k) == 0);
                unsigned long long a = sm.sortbuf[i], b = sm.sortbuf[p];
                bool sw = up ? (a > b) : (a < b);
                if (sw) { sm.sortbuf[i] = b; sm.sortbuf[p] = a; }
                __syncthreads();
            }
        }
        for (int l = t; l < 2048; l += 1024) keys[base + l] = sm.sortbuf[l];
    }
    if (bid == 0 && t == 0) { *ecntE = 0; *nvD = 0; }
    __threadfence();
    grid.sync();

    // ------- Phase S2: 2 blocks, fused k=4096 + k=8192 merge + gather -----
    if (bid < 2) {
        int half = bid;
        int base = half << 12;
        for (int l = t; l < 8192; l += 1024) sm.sortbuf[l] = keys[l];
        __syncthreads();
        // k=4096 merge on the full array
        for (int j = 2048; j > 0; j >>= 1) {
            for (int t2 = t; t2 < 4096; t2 += 1024) {
                int i = ((t2 & ~(j - 1)) << 1) | (t2 & (j - 1));
                int p = i | j;
                bool up = ((i & 4096) == 0);
                unsigned long long a = sm.sortbuf[i], b = sm.sortbuf[p];
                bool sw = up ? (a > b) : (a < b);
                if (sw) { sm.sortbuf[i] = b; sm.sortbuf[p] = a; }
            }
            __syncthreads();
        }
        // k=8192, j=4096: min -> low half, max -> high half (all ascending)
        unsigned long long v4[4];
#pragma unroll
        for (int q = 0; q < 4; ++q) {
            int l = t + (q << 10);
            unsigned long long a = sm.sortbuf[l], b = sm.sortbuf[l + 4096];
            v4[q] = half ? (a > b ? a : b) : (a > b ? b : a);
        }
        __syncthreads();
#pragma unroll
        for (int q = 0; q < 4; ++q) sm.sortbuf[base + t + (q << 10)] = v4[q];
        __syncthreads();
        // j=2048..1 on own half (all ascending at k=8192)
        for (int j = 2048; j > 0; j >>= 1) {
            for (int t2 = t; t2 < 2048; t2 += 1024) {
                int i = base + (((t2 & ~(j - 1)) << 1) | (t2 & (j - 1)));
                int p = i | j;
                unsigned long long a = sm.sortbuf[i], b = sm.sortbuf[p];
                if (a > b) { sm.sortbuf[i] = b; sm.sortbuf[p] = a; }
            }
            __syncthreads();
        }
        // gather: sb/order/validw; nv accumulated (valid boxes = ranks [0,nv))
        for (int l = t; l < 4096; l += 1024) {
            int gi = base + l;
            unsigned int o = (unsigned int)(sm.sortbuf[gi] & 0xffffffffull);
            order[gi] = o;
            sb[gi] = ((const float4*)bboxes)[o];
            float c0 = conf[2 * o], c1 = conf[2 * o + 1];
            unsigned long long vb = __ballot((c0 > THR_C) || (c1 > THR_C));
            if ((gi & 63) == 0) {
                validw[gi >> 6] = vb;
                atomicAdd(nvD, __popcll(vb));
            }
        }
    }
    __threadfence();
    grid.sync();

    // --------- Phase P: all blocks build edge list over nv triangle --------
    {
        int nv = *nvD;
        for (int tile = bid; tile < 8 * 128; tile += 256) {
            int iblk = tile & 7;             // 8 i-tiles of 1024 rows
            int w = tile >> 3;               // 128 j-tiles of 64 cols
            int ibase = iblk << 10, jbase = w << 6;
            if (ibase >= nv || jbase >= nv || jbase + 63 <= ibase) continue; // uniform
            if (t < 64) {
                float4 c = sb[jbase + t];
                sm.p.cb[t] = c;
                sm.p.carea[t] = (c.z - c.x) * (c.w - c.y);
            }
            __syncthreads();
            int i = ibase + t;
            unsigned long long bits = 0ull;
            if (i < nv && jbase + 63 > i) {
                float4 r = sb[i];
                float ra = (r.z - r.x) * (r.w - r.y);
#pragma unroll 8
                for (int b = 0; b < 64; ++b) {
                    float4 c = sm.p.cb[b];
                    float iw = fminf(r.z, c.z) - fmaxf(r.x, c.x);
                    float ih = fminf(r.w, c.w) - fmaxf(r.y, c.y);
                    iw = fmaxf(iw, 0.0f);
                    ih = fmaxf(ih, 0.0f);
                    float inter = iw * ih;
                    float iou = inter / (ra + sm.p.carea[b] - inter + EPS_C);
                    if ((iou > IOU_THR_C) && ((jbase + b) > i)) bits |= (1ull << b);
                }
            }
            // drop invalid targets (ranks >= nv can never be kept)
            unsigned long long tmask = (jbase + 64 <= nv) ? ~0ull
                                       : ((1ull << (nv - jbase)) - 1ull);
            unsigned long long ebits = bits & tmask;
            int ec = __popcll(ebits);
            int pre = ec;
#pragma unroll
            for (int d = 1; d < 64; d <<= 1) {
                int vv = __shfl_up(pre, d, 64);
                if (lane >= d) pre += vv;
            }
            int tot = __shfl(pre, 63, 64);
            if (tot > 0) {
                int ebase = 0;
                if (lane == 63) ebase = atomicAdd(ecntE, tot);
                ebase = __shfl(ebase, 63, 64);
                int idx = ebase + pre - ec;
                unsigned long long tb = ebits;
                while (tb) {
                    int b = __builtin_ctzll(tb); tb &= tb - 1;
                    if (idx < ecap)
                        edges[idx] = ((unsigned int)i << 13) | (unsigned int)(jbase + b);
                    ++idx;
                }
            }
            __syncthreads();   // before next tile reuses cb
        }
    }
    __threadfence();
    grid.sync();

    // ---------- Phase J: block 0 Jacobi fixpoint (greedy NMS) -------------
    if (bid == 0) {
        int cnt = *ecntE;
        if (t < NW) { unsigned long long v = validw[t]; sm.j.vL[t] = v; sm.j.kL[t] = v; }
        if (t == 0) { sm.j.chg[0] = 0; sm.j.chg[1] = 0; sm.j.chg[2] = 0; }
        if (cnt <= ecap) {
            int lim = cnt < LCAP ? cnt : LCAP;
            for (int e = t; e < lim; e += 1024) sm.j.eL[e] = edges[e];
        }
        __syncthreads();
        if (cnt <= ecap) {
            for (int it = 0; it < N_BOX; ++it) {
                if (t < NW) sm.j.tL[t] = 0ull;
                __syncthreads();
                for (int e = t; e < cnt; e += 1024) {
                    unsigned int ed = (e < LCAP) ? sm.j.eL[e] : edges[e];
                    int src = (int)(ed >> 13);
                    if ((sm.j.kL[src >> 6] >> (src & 63)) & 1ull) {
                        int tg = (int)(ed & 8191u);
                        atomicOr(&sm.j.tL[tg >> 6], 1ull << (tg & 63));
                    }
                }
                __syncthreads();
                if (t < NW) {
                    unsigned long long nk = sm.j.vL[t] & ~sm.j.tL[t];
                    if (nk != sm.j.kL[t]) sm.j.chg[it % 3] = 1;
                    sm.j.kL[t] = nk;
                }
                if (t == 0) sm.j.chg[(it + 2) % 3] = 0; // reset 2 barriers early
                __syncthreads();
                if (sm.j.chg[it % 3] == 0) break;       // uniform after barrier
            }
        } else {
            // fallback: serial greedy, IoU recomputed on the fly (one wave)
            if (t < NW) sm.j.tL[t] = ~sm.j.vL[t];
            __syncthreads();
            if (t < 64) {
                for (int i = 0; i < N_BOX - 1; ++i) {
                    bool kept = !((sm.j.tL[i >> 6] >> (i & 63)) & 1ull);
                    if (kept) {
                        float4 r = sb[i];
                        float ra = (r.z - r.x) * (r.w - r.y);
                        for (int jj = i + 1 + lane; jj < N_BOX; jj += 64) {
                            float4 c = sb[jj];
                            float ca = (c.z - c.x) * (c.w - c.y);
                            float iw = fminf(r.z, c.z) - fmaxf(r.x, c.x);
                            float ih = fminf(r.w, c.w) - fmaxf(r.y, c.y);
                            iw = fmaxf(iw, 0.0f);
                            ih = fmaxf(ih, 0.0f);
                            float inter = iw * ih;
                            float iou = inter / (ra + ca - inter + EPS_C);
                            if (iou > IOU_THR_C)
                                atomicOr(&sm.j.tL[jj >> 6], 1ull << (jj & 63));
                        }
                    }
                }
            }
            __syncthreads();
            if (t < NW) sm.j.kL[t] = sm.j.vL[t] & ~sm.j.tL[t];
            __syncthreads();
        }
        if (t < NW) keepK[t] = sm.j.kL[t];
    }
    __threadfence();
    grid.sync();

    // ---------- Phase O: blocks 0-7 write (N,6) output --------------------
    if (bid < 8) {
        int i = bid * 1024 + t;
        float kf = ((keepK[i >> 6] >> (i & 63)) & 1ull) ? 1.0f : 0.0f;
        float4 b = sb[i];
        unsigned int o = order[i];
        float s = kScaler * kf;
        out[i * 6 + 0] = b.x * s;
        out[i * 6 + 1] = b.y * s;
        out[i * 6 + 2] = b.z * s;
        out[i * 6 + 3] = b.w * s;
        out[i * 6 + 4] = conf[2 * o] * kf;
        out[i * 6 + 5] = conf[2 * o + 1] * kf;
    }
}

extern "C" void kernel_launch(void* const* d_in, const int* in_sizes, int n_in,
                              void* d_out, int out_size, void* d_ws, size_t ws_size,
                              hipStream_t stream) {
    const float* cls_conf = (const float*)d_in[0];   // (8192, 2)
    const float* bboxes   = (const float*)d_in[1];   // (8192, 4)
    float* out = (float*)d_out;                      // (8192, 6)

    char* ws = (char*)d_ws;
    unsigned long long* keys   = (unsigned long long*)(ws + 0);        //  64 KiB
    float4*             sb     = (float4*)(ws + 65536);                // 128 KiB
    unsigned int*       order  = (unsigned int*)(ws + 196608);         //  32 KiB
    unsigned long long* validw = (unsigned long long*)(ws + 229376);   //   1 KiB
    int*                ecntE  = (int*)(ws + 230400);                  //   4 B
    int*                nvD    = (int*)(ws + 230408);                  //   4 B
    unsigned long long* keepK  = (unsigned long long*)(ws + 230912);   //   1 KiB
    const size_t EDGE_OFF = 237568;
    unsigned int*       edges  = (unsigned int*)(ws + EDGE_OFF);
    size_t avail = (ws_size > EDGE_OFF + 16) ? (ws_size - EDGE_OFF) / 4 : 0;
    int ecap = (int)(avail > (size_t)ECAP_MAX ? (size_t)ECAP_MAX : avail);

    void* args[] = { (void*)&cls_conf, (void*)&bboxes, (void*)&keys, (void*)&sb,
                     (void*)&order, (void*)&validw, (void*)&ecntE, (void*)&nvD,
                     (void*)&edges, (void*)&keepK, (void*)&out, (void*)&ecap };
    hipLaunchCooperativeKernel((void*)mega_kernel, dim3(256), dim3(1024),
                               args, 0, stream);
}